// Round 6
// baseline (96.264 us; speedup 1.0000x reference)
//
#include <hip/hip_runtime.h>
#include <math.h>

// NoisyTopkRouter: B=4 S=4096 D=2048 E=16 K=2, TEMPERATURE=1. rows = 16384.
// out layout (fp32): router_output [16384*16] | indices-as-float [16384*2] | aux_loss [1]
// Round 6: 256 blocks x 64 rows, 16 waves x 128-d slice, 1024-thread blocks.
//  - R=8 rows/thread (halves W VMEM instrs vs round 5: cost model 2+12/C+16/R).
//  - W ping-pong wp[2][4] register pipeline from global (L2-hot, 8-addr broadcast).
//  - x dbuf LDS [2][64][8] per wave, linear layout (<=2-way bank aliasing = free),
//    register prefetch, no barriers in main loop.
//  - 16-wave partial reduce: 4 LDS tree phases over 8 x 8KB regions (64KB static).
//  - launch_bounds(1024,4): VGPR cap 128 >= ~100 demand (round-2 spill lesson).

#define DDIM 2048
#define NEXP 16
#define RPB 64             // rows per block
#define WAVE_D 128         // d-slice per wave (16 waves cover 2048)
#define NCHNK 16           // chunks of 8 d per wave
#define NGRP 32            // 4-d groups per wave (WAVE_D/4)
#define IDX_OFF 262144
#define AUX_OFF 294912
#define NBLK 256

__global__ __launch_bounds__(1024, 4) void router_main_k(
    const float* __restrict__ x, const float* __restrict__ wr,
    const float* __restrict__ br, const float* __restrict__ wn,
    const float* __restrict__ bn, const float* __restrict__ eps,
    float* __restrict__ out, float* __restrict__ wsp) {
  __shared__ float smem[16384];  // 65536 B: 16 x-dbuf regions / 8 reduce regions

  const int tid  = threadIdx.x;
  const int wave = tid >> 6;
  const int lane = tid & 63;
  const int rg   = lane >> 3;        // 0..7 -> rows {rg + 8i}, i = 0..7
  const int q    = lane & 7;         // col group: q<4 route cols 4q..; q>=4 noise
  const int row_base = blockIdx.x * RPB;

  float* xregion = smem + wave * 1024;   // [2][64][8] dbuf x slice

  // ---- x staging map: lane covers f4 #lane and #(lane+64) of each 128-f4 chunk
  // f -> row = f>>1, dgroup = f&1; LDS addr = f*4 (linear [64][8])
  const float* xg0 = x + (size_t)(row_base + (lane >> 1)) * DDIM + wave * WAVE_D + (lane & 1) * 4;
  const float* xg1 = xg0 + (size_t)32 * DDIM;
  const int ls0 = lane * 4;
  const int ls1 = lane * 4 + 256;

  // ---- per-lane W pointer (route for q<4, noise for q>=4)
  const float* wbase = (q < 4 ? wr : wn) + (size_t)(wave * WAVE_D) * NEXP + (q & 3) * 4;

  float4 acc[8];
  #pragma unroll
  for (int i = 0; i < 8; ++i) acc[i] = make_float4(0.f, 0.f, 0.f, 0.f);

  float4 wp[2][4];
  float4 xp0, xp1;

  // ---- prologue: W group 0 + x chunk 0 ----
  #pragma unroll
  for (int j = 0; j < 4; ++j) wp[0][j] = *(const float4*)(wbase + j * NEXP);
  xp0 = *(const float4*)(xg0);
  xp1 = *(const float4*)(xg1);
  *(float4*)(xregion + ls0) = xp0;
  *(float4*)(xregion + ls1) = xp1;

  for (int k = 0; k < NCHNK; ++k) {
    const float* xb = xregion + (k & 1) * 512;
    #pragma unroll
    for (int gg = 0; gg < 2; ++gg) {
      const int G = (k << 1) + gg;
      // prefetch W for group G+1 into the other bank
      if (G + 1 < NGRP) {
        const float* wl = wbase + (size_t)(G + 1) * 4 * NEXP;
        #pragma unroll
        for (int j = 0; j < 4; ++j) wp[gg ^ 1][j] = *(const float4*)(wl + j * NEXP);
      }
      // prefetch x chunk k+1 (issued at gg==0, written after gg==1 compute)
      if (gg == 0 && k + 1 < NCHNK) {
        xp0 = *(const float4*)(xg0 + (k + 1) * 8);
        xp1 = *(const float4*)(xg1 + (k + 1) * 8);
      }
      // compute: 8 rows x 4 cols x 4 d
      #pragma unroll
      for (int i = 0; i < 8; ++i) {
        const float4 xv = *(const float4*)(xb + (rg + 8 * i) * 8 + (gg << 2));
        acc[i].x = fmaf(xv.w, wp[gg][3].x, fmaf(xv.z, wp[gg][2].x, fmaf(xv.y, wp[gg][1].x, fmaf(xv.x, wp[gg][0].x, acc[i].x))));
        acc[i].y = fmaf(xv.w, wp[gg][3].y, fmaf(xv.z, wp[gg][2].y, fmaf(xv.y, wp[gg][1].y, fmaf(xv.x, wp[gg][0].y, acc[i].y))));
        acc[i].z = fmaf(xv.w, wp[gg][3].z, fmaf(xv.z, wp[gg][2].z, fmaf(xv.y, wp[gg][1].z, fmaf(xv.x, wp[gg][0].z, acc[i].z))));
        acc[i].w = fmaf(xv.w, wp[gg][3].w, fmaf(xv.z, wp[gg][2].w, fmaf(xv.y, wp[gg][1].w, fmaf(xv.x, wp[gg][0].w, acc[i].w))));
      }
      if (gg == 1 && k + 1 < NCHNK) {
        float* xw = xregion + ((k + 1) & 1) * 512;
        *(float4*)(xw + ls0) = xp0;
        *(float4*)(xw + ls1) = xp1;
      }
    }
  }

  // ---- 16-wave tree reduction over 8 x [64][32] regions (swizzled col ^ row) ----
  const int psw = (q ^ rg) << 2;   // conflict-free: 8 rg-lanes -> 8 distinct bank quads

#define DUMP_R(Rg) { float* pr = smem + (Rg) * 2048; \
    _Pragma("unroll") for (int i = 0; i < 8; ++i) \
      *(float4*)(pr + (rg + 8 * i) * 32 + psw) = acc[i]; }
#define ADD_R(Rg) { const float* pr = smem + (Rg) * 2048; \
    _Pragma("unroll") for (int i = 0; i < 8; ++i) { \
      float4 a = *(const float4*)(pr + (rg + 8 * i) * 32 + psw); \
      acc[i].x += a.x; acc[i].y += a.y; acc[i].z += a.z; acc[i].w += a.w; } }

  __syncthreads();
  if (wave >= 8) DUMP_R(wave - 8);
  __syncthreads();
  if (wave < 8)  ADD_R(wave);
  __syncthreads();
  if (wave >= 4 && wave < 8) DUMP_R(wave - 4);
  __syncthreads();
  if (wave < 4)  ADD_R(wave);
  __syncthreads();
  if (wave >= 2 && wave < 4) DUMP_R(wave - 2);
  __syncthreads();
  if (wave < 2)  ADD_R(wave);
  __syncthreads();
  if (wave == 1) DUMP_R(0);
  __syncthreads();

  // ---- wave 0: final add, dump, per-row epilogue (64 rows on 64 lanes) ----
  if (wave == 0) {
    ADD_R(0);
    DUMP_R(0);   // same-wave ds_write -> ds_read: compiler inserts lgkmcnt waits

    const int row_l = lane;
    const int row_g = row_base + row_l;
    float c[32];
    #pragma unroll
    for (int g = 0; g < 8; ++g) {
      float4 a = *(const float4*)(smem + row_l * 32 + ((g ^ (row_l & 7)) << 2));
      c[g * 4 + 0] = a.x; c[g * 4 + 1] = a.y; c[g * 4 + 2] = a.z; c[g * 4 + 3] = a.w;
    }

    float brv[16], bnv[16], ev[16];
    #pragma unroll
    for (int g = 0; g < 4; ++g) {
      *(float4*)(brv + g * 4) = *(const float4*)(br + g * 4);
      *(float4*)(bnv + g * 4) = *(const float4*)(bn + g * 4);
      *(float4*)(ev  + g * 4) = *(const float4*)(eps + (size_t)row_g * NEXP + g * 4);
    }

    float s[16];
    #pragma unroll
    for (int e = 0; e < 16; ++e) {
      float lg = c[e] + brv[e];
      float nz = c[16 + e] + bnv[e];
      float sp = fmaxf(nz, 0.f) + log1pf(expf(-fabsf(nz)));  // stable softplus
      s[e] = lg + ev[e] * sp;                                 // TEMPERATURE == 1
    }

    // top-2 (ties -> lowest index, matching lax.top_k)
    float b1 = s[0]; int i1 = 0;
    #pragma unroll
    for (int e = 1; e < 16; ++e) { if (s[e] > b1) { b1 = s[e]; i1 = e; } }
    float b2 = -INFINITY; int i2 = 0;
    #pragma unroll
    for (int e = 0; e < 16; ++e) { if (e != i1 && s[e] > b2) { b2 = s[e]; i2 = e; } }

    float t2 = expf(b2 - b1);
    float p1 = 1.f / (1.f + t2);
    float p2 = t2 / (1.f + t2);

    float v[16];
    #pragma unroll
    for (int e = 0; e < 16; ++e)
      v[e] = (e == i1) ? p1 : ((e == i2) ? p2 : 0.f);

    float* orow = out + (size_t)row_g * NEXP;
    *(float4*)(orow + 0)  = make_float4(v[0], v[1], v[2], v[3]);
    *(float4*)(orow + 4)  = make_float4(v[4], v[5], v[6], v[7]);
    *(float4*)(orow + 8)  = make_float4(v[8], v[9], v[10], v[11]);
    *(float4*)(orow + 12) = make_float4(v[12], v[13], v[14], v[15]);

    float* oidx = out + IDX_OFF + (size_t)row_g * 2;
    *(float2*)oidx = make_float2((float)i1, (float)i2);

    // per-block expert-prob sums over 64 rows (full-wave butterfly)
    #pragma unroll
    for (int m = 1; m < 64; m <<= 1) {
      #pragma unroll
      for (int e = 0; e < 16; ++e) v[e] += __shfl_xor(v[e], m, 64);
    }
    if (lane == 0) {
      float* wpo = wsp + (size_t)blockIdx.x * 16;
      *(float4*)(wpo + 0)  = make_float4(v[0], v[1], v[2], v[3]);
      *(float4*)(wpo + 4)  = make_float4(v[4], v[5], v[6], v[7]);
      *(float4*)(wpo + 8)  = make_float4(v[8], v[9], v[10], v[11]);
      *(float4*)(wpo + 12) = make_float4(v[12], v[13], v[14], v[15]);
    }
  }
}

__global__ void router_aux_k(const float* __restrict__ wsp, float* __restrict__ out_aux) {
  __shared__ float red[16][17];
  __shared__ float sq[16];
  const int t = threadIdx.x;
  const int e = t & 15;
  const int g = t >> 4;
  float ssum = 0.f;
  #pragma unroll
  for (int b = 0; b < 16; ++b) ssum += wsp[(size_t)(g * 16 + b) * 16 + e];
  red[g][e] = ssum;
  __syncthreads();
  if (t < 16) {
    float tot = 0.f;
    #pragma unroll
    for (int gg = 0; gg < 16; ++gg) tot += red[gg][t];
    float diff = tot * (1.f / 16384.f) - 0.0625f;
    sq[t] = diff * diff;
  }
  __syncthreads();
  if (t == 0) {
    float a = 0.f;
    #pragma unroll
    for (int i = 0; i < 16; ++i) a += sq[i];
    *out_aux = a;
  }
}

extern "C" void kernel_launch(void* const* d_in, const int* in_sizes, int n_in,
                              void* d_out, int out_size, void* d_ws, size_t ws_size,
                              hipStream_t stream) {
  const float* x   = (const float*)d_in[0];
  const float* wr  = (const float*)d_in[1];
  const float* br  = (const float*)d_in[2];
  const float* wn  = (const float*)d_in[3];
  const float* bn  = (const float*)d_in[4];
  const float* eps = (const float*)d_in[5];
  float* out = (float*)d_out;
  float* wsp = (float*)d_ws;  // 256 blocks * 16 floats = 16 KB partials

  router_main_k<<<NBLK, 1024, 0, stream>>>(x, wr, br, wn, bn, eps, out, wsp);
  router_aux_k<<<1, 256, 0, stream>>>(wsp, out + AUX_OFF);
}